// Round 2
// baseline (474.605 us; speedup 1.0000x reference)
//
#include <hip/hip_runtime.h>
#include <cstddef>

#define NN 8192
#define CC 128

// ---- bf16 pack helpers ----
static __device__ inline unsigned f2bf_pack(float a, float b) {
  unsigned ua = __builtin_bit_cast(unsigned, a);
  ua += 0x7fffu + ((ua >> 16) & 1u);
  unsigned ub = __builtin_bit_cast(unsigned, b);
  ub += 0x7fffu + ((ub >> 16) & 1u);
  return (ua >> 16) | (ub & 0xffff0000u);
}
static __device__ inline float bf_lo(unsigned u) { return __builtin_bit_cast(float, u << 16); }
static __device__ inline float bf_hi(unsigned u) { return __builtin_bit_cast(float, u & 0xffff0000u); }

// ---- async global->LDS (16B per lane, no VGPR transit) ----
typedef const __attribute__((address_space(1))) void gvoid_t;
typedef __attribute__((address_space(3))) void lvoid_t;
static __device__ inline void glds16(const float* g, float* l) {
  __builtin_amdgcn_global_load_lds((gvoid_t*)g, (lvoid_t*)l, 16, 0, 0);
}

// ---------------- CSR build ----------------

__global__ __launch_bounds__(256) void count_deg_int_k(const int* __restrict__ dst, int* degi, int E) {
  int i = blockIdx.x * 256 + threadIdx.x;
  if (i < E) atomicAdd(&degi[dst[i]], 1);
}

__global__ __launch_bounds__(256) void dinv_k(const int* __restrict__ degi, float* __restrict__ dinv, int n) {
  int i = blockIdx.x * 256 + threadIdx.x;
  if (i < n) dinv[i] = rsqrtf((float)(degi[i] + 1));
}

__global__ __launch_bounds__(256) void scan_k(const int* __restrict__ degi, int* __restrict__ rowstart,
                                              int* __restrict__ cursor) {
  __shared__ int partial[256];
  int t = threadIdx.x;
  int base = t * 32;
  int local[32];
  int s = 0;
#pragma unroll
  for (int i = 0; i < 32; ++i) { local[i] = s; s += degi[base + i]; }
  partial[t] = s;
  __syncthreads();
  for (int off = 1; off < 256; off <<= 1) {
    int v = (t >= off) ? partial[t - off] : 0;
    __syncthreads();
    partial[t] += v;
    __syncthreads();
  }
  int offset = partial[t] - s;
#pragma unroll
  for (int i = 0; i < 32; ++i) {
    rowstart[base + i] = offset + local[i];
    cursor[base + i] = offset + local[i];
  }
  if (t == 255) rowstart[NN] = offset + s;
}

__global__ __launch_bounds__(256) void bucket_k(const int* __restrict__ src, const int* __restrict__ dst,
    int* __restrict__ cursor, int* __restrict__ col, int E) {
  int e = blockIdx.x * 256 + threadIdx.x;
  if (e >= E) return;
  int d = dst[e];
  int pos = atomicAdd(&cursor[d], 1);
  col[pos] = src[e];
}

// h1 = dd*(sum_in xws[s] + xws[d]) + conv_b + x   where xws = (x@W)*dinv[row]
__global__ __launch_bounds__(256) void gather_k(const int* __restrict__ rowstart, const int* __restrict__ col,
    const float* __restrict__ xws, const float* __restrict__ dinv, const float* __restrict__ cb,
    const float* __restrict__ x, float* __restrict__ h1) {
  int d = blockIdx.x * 2 + (threadIdx.x >> 7);
  int c = threadIdx.x & 127;
  int j0 = rowstart[d], j1 = rowstart[d + 1];
  float dd = dinv[d];
  float sum = 0.f;
  float v = 0.f;
  if (j0 < j1) v = xws[(size_t)col[j0] * CC + c];
  for (int j = j0; j < j1; ++j) {
    float v_next = 0.f;
    if (j + 1 < j1) v_next = xws[(size_t)col[j + 1] * CC + c];
    sum += v;
    v = v_next;
  }
  int idx = d * CC + c;
  sum += xws[idx];
  h1[idx] = sum * dd + cb[c] + x[idx];
}

// ---------------- BN helpers ----------------

__global__ __launch_bounds__(256) void bn_stats_k(const float* __restrict__ X,
    float* __restrict__ sums, float* __restrict__ sumsq) {
  int t = threadIdx.x;
  int c = t & 127, rg = t >> 7;
  int r0 = blockIdx.x * 64;
  float s = 0.f, sq = 0.f;
  for (int i = 0; i < 32; ++i) {
    float v = X[(size_t)(r0 + rg + 2 * i) * CC + c];
    s += v; sq += v * v;
  }
  atomicAdd(&sums[c], s);
  atomicAdd(&sumsq[c], sq);
}

__global__ __launch_bounds__(256) void combine_k(const float* __restrict__ h1, const float* __restrict__ h2,
    const float* __restrict__ st, const float* __restrict__ g1, const float* __restrict__ be1,
    const float* __restrict__ g2, const float* __restrict__ be2, float* __restrict__ out) {
  int idx = blockIdx.x * 256 + threadIdx.x;
  int c = idx & 127;
  float mu1 = st[c] * (1.f / NN);
  float var1 = st[128 + c] * (1.f / NN) - mu1 * mu1;
  float sc1 = g1[c] * rsqrtf(var1 + 1e-5f);
  float sh1 = be1[c] - mu1 * sc1;
  float mu2 = st[256 + c] * (1.f / NN);
  float var2 = st[384 + c] * (1.f / NN) - mu2 * mu2;
  float sc2 = g2[c] * rsqrtf(var2 + 1e-5f);
  float sh2 = be2[c] - mu2 * sc2;
  out[idx] = sc1 * h1[idx] + sh1 + sc2 * h2[idx] + sh2;
}

__global__ __launch_bounds__(256) void bn_apply_k(const float* __restrict__ h, const float* __restrict__ st,
    const float* __restrict__ g3, const float* __restrict__ be3, float* __restrict__ out) {
  int idx = blockIdx.x * 256 + threadIdx.x;
  int c = idx & 127;
  float mu = st[512 + c] * (1.f / NN);
  float var = st[640 + c] * (1.f / NN) - mu * mu;
  float sc = g3[c] * rsqrtf(var + 1e-5f);
  float sh = be3[c] - mu * sc;
  out[idx] = sc * h[idx] + sh;
}

// ---------------- fp32 GEMM ----------------
__global__ __launch_bounds__(256) void gemm_k(const float* __restrict__ A, const float* __restrict__ W,
    const float* __restrict__ bias, const float* __restrict__ resid, const float* __restrict__ dscale,
    float* __restrict__ out, int M, int N, int K, float scale, int relu) {
  __shared__ float As[64 * 132];
  __shared__ float Ws[128 * 64];
  int t = threadIdx.x;
  int ty = t >> 4, tx = t & 15;
  int row0 = blockIdx.x * 64, n0 = blockIdx.y * 64;
  float acc[4][4] = {};
  for (int kc = 0; kc < K; kc += 128) {
#pragma unroll
    for (int j = 0; j < 8; ++j) {
      int f = t + 256 * j;
      int r = f >> 5, c4 = f & 31;
      *(float4*)(As + r * 132 + c4 * 4) = *(const float4*)(A + (size_t)(row0 + r) * K + kc + c4 * 4);
    }
#pragma unroll
    for (int j = 0; j < 8; ++j) {
      int f = t + 256 * j;
      int kr = f >> 4, c4 = f & 15;
      *(float4*)(Ws + kr * 64 + c4 * 4) = *(const float4*)(W + (size_t)(kc + kr) * N + n0 + c4 * 4);
    }
    __syncthreads();
    for (int k0 = 0; k0 < 128; k0 += 4) {
      float a[4][4], b[4][4];
#pragma unroll
      for (int i = 0; i < 4; ++i) {
        float4 t4 = *(const float4*)(As + (4 * ty + i) * 132 + k0);
        a[i][0] = t4.x; a[i][1] = t4.y; a[i][2] = t4.z; a[i][3] = t4.w;
      }
#pragma unroll
      for (int kk = 0; kk < 4; ++kk) {
        float4 t4 = *(const float4*)(Ws + (k0 + kk) * 64 + 4 * tx);
        b[kk][0] = t4.x; b[kk][1] = t4.y; b[kk][2] = t4.z; b[kk][3] = t4.w;
      }
#pragma unroll
      for (int kk = 0; kk < 4; ++kk)
#pragma unroll
        for (int i = 0; i < 4; ++i)
#pragma unroll
          for (int j = 0; j < 4; ++j)
            acc[i][j] += a[i][kk] * b[kk][j];
    }
    __syncthreads();
  }
  float4 bv = make_float4(0.f, 0.f, 0.f, 0.f);
  if (bias) bv = *(const float4*)(bias + n0 + 4 * tx);
#pragma unroll
  for (int i = 0; i < 4; ++i) {
    int row = row0 + 4 * ty + i;
    float ds = dscale ? dscale[row] : 1.f;
    float4 r;
    r.x = (acc[i][0] + bv.x) * scale * ds;
    r.y = (acc[i][1] + bv.y) * scale * ds;
    r.z = (acc[i][2] + bv.z) * scale * ds;
    r.w = (acc[i][3] + bv.w) * scale * ds;
    if (relu) { r.x = fmaxf(r.x, 0.f); r.y = fmaxf(r.y, 0.f); r.z = fmaxf(r.z, 0.f); r.w = fmaxf(r.w, 0.f); }
    size_t o = (size_t)row * N + n0 + 4 * tx;
    if (resid) {
      float4 rv = *(const float4*)(resid + o);
      r.x += rv.x; r.y += rv.y; r.z += rv.z; r.w += rv.w;
    }
    *(float4*)(out + o) = r;
  }
}

// ---------------- flash attention v3: 4 q/thread (LDS amortization) x 2 waves/SIMD ----------------
// Geometry: 32 q/wave (8 qq-lanes x 4 r), 8 key-splits of 64 keys, grid 2048 single-wave blocks
// = 8 blocks/CU (2 waves/SIMD), LDS 16KB/block (2 x [K 2KB | V 2KB | bias 4KB]) -> 10 fit.
// Per-CU LDS b128 traffic is keys*8/q_per_wave -> back to v1's amortized level (v2 was 4x).
// Split decode s = orig&7 IS the XCD swizzle: XCD x owns split x; its K/V slice (1MB) L2-resident.
// Partials: 8 splits x 2.1MB bf16 -> regions xw(s0,1), h2pre(s2,3), d_out(s4,5), outbuf(s6,7);
// merge writes result to vb (free after attn); wo-gemm reads vb. h3pre(=vb) written only after.
// K/V LDS reads broadcast across 8 q-lanes; h vs h+4 2-way alias free; j-rotation kills h-stride
// conflicts. Bias staged with kk-rotation by q (q = qq+8r so rotation varies per lane -> 2-way max).
// No max-tracking: scores O(9) << 88, raw exp safe.
__global__ __launch_bounds__(64, 2) void attn_k(const float* __restrict__ Q, const float* __restrict__ K,
    const float* __restrict__ V, const float* __restrict__ bias,
    unsigned* __restrict__ p0, unsigned* __restrict__ p1,
    unsigned* __restrict__ p2, unsigned* __restrict__ p3, float* __restrict__ lbuf) {
  __shared__ float SM[2][2048];   // per buf: K[0..512) V[512..1024) B[1024..2048)
  const int t = threadIdx.x;
  const int orig = blockIdx.x;
  const int s = orig & 7;         // split; doubles as XCD-affinity
  const int qtg = orig >> 3;      // global q-tile 0..255
  const int b = qtg >> 4;
  const int qt = qtg & 15;
  const int qq = t >> 3;
  const int h = t & 7;
  const int node_t = b * 512 + qt * 32;
  const int key0 = s * 64;
  const size_t kvb = ((size_t)b * 512 + key0) * CC;
  const float* bbase = bias + ((size_t)node_t * 512 + key0) * 8;

  // rotated Q fragments: qf[r][j] holds element group (j+h)&3 of row node_t+qq+8r, head h
  float4 qf[4][4];
#pragma unroll
  for (int r = 0; r < 4; ++r)
#pragma unroll
    for (int j = 0; j < 4; ++j)
      qf[r][j] = *(const float4*)(Q + (size_t)(node_t + qq + 8 * r) * CC + h * 16 + (((j + h) & 3) << 2));

  float4 acc[4][4];
  float l[4] = {0.f, 0.f, 0.f, 0.f};
#pragma unroll
  for (int r = 0; r < 4; ++r)
#pragma unroll
    for (int j = 0; j < 4; ++j) acc[r][j] = make_float4(0.f, 0.f, 0.f, 0.f);

  auto stage = [&](int ch, int bf) {
    const float* kg = K + kvb + ch * 512;    // 4 keys x 128 floats
    const float* vg = V + kvb + ch * 512;
    float* ksl = &SM[bf][0];
    float* vsl = &SM[bf][512];
    float* bsl = &SM[bf][1024];
#pragma unroll
    for (int i = 0; i < 2; ++i) {
      glds16(kg + i * 256 + t * 4, ksl + i * 256);
      glds16(vg + i * 256 + t * 4, vsl + i * 256);
    }
    // bias: LDS slot [q][kkp][hq] (q=i*8+(t>>3), kkp=(t>>1)&3, hq=t&1); source kk=(kkp-q)&3
#pragma unroll
    for (int i = 0; i < 4; ++i) {
      int q = i * 8 + (t >> 3);
      int kkp = (t >> 1) & 3;
      int hq = t & 1;
      int kks = (kkp - q) & 3;
      glds16(bbase + (size_t)q * 4096 + (size_t)(ch * 4 + kks) * 8 + hq * 4, bsl + i * 256);
    }
  };

  stage(0, 0);
  for (int ch = 0; ch < 16; ++ch) {
    int bf = ch & 1;
    if (ch + 1 < 16) stage(ch + 1, bf ^ 1);
    asm volatile("" ::: "memory");
    if (ch + 1 < 16) __builtin_amdgcn_s_waitcnt(0x0F78);  // vmcnt(8): this chunk done, next 8 in flight
    else             __builtin_amdgcn_s_waitcnt(0x0F70);  // vmcnt(0)
    asm volatile("" ::: "memory");
    const float* ksl = &SM[bf][0];
    const float* vsl = &SM[bf][512];
    const float* bsl = &SM[bf][1024];
#pragma unroll
    for (int kk = 0; kk < 4; ++kk) {
      float4 kr[4], vr[4];
#pragma unroll
      for (int j = 0; j < 4; ++j) {
        int off = kk * 128 + h * 16 + (((j + h) & 3) << 2);
        kr[j] = *(const float4*)(ksl + off);
        vr[j] = *(const float4*)(vsl + off);
      }
      int brot = ((kk + qq) & 3) << 3;
#pragma unroll
      for (int r = 0; r < 4; ++r) {
        float sc = bsl[qq * 32 + r * 256 + brot + h];
#pragma unroll
        for (int j = 0; j < 4; ++j)
          sc += qf[r][j].x * kr[j].x + qf[r][j].y * kr[j].y
              + qf[r][j].z * kr[j].z + qf[r][j].w * kr[j].w;
        float p = __expf(sc);
        l[r] += p;
#pragma unroll
        for (int j = 0; j < 4; ++j) {
          acc[r][j].x += p * vr[j].x; acc[r][j].y += p * vr[j].y;
          acc[r][j].z += p * vr[j].z; acc[r][j].w += p * vr[j].w;
        }
      }
    }
  }

  // write bf16 raw-sum partials (un-rotate group order) + l
  unsigned* preg = (s < 4) ? ((s < 2) ? p0 : p1) : ((s < 6) ? p2 : p3);
  unsigned* pbase = preg + (size_t)(s & 1) * (NN * CC / 2);
#pragma unroll
  for (int r = 0; r < 4; ++r) {
    int node = node_t + qq + 8 * r;
    int slot = (node * 8 + h) * 8;
    unsigned u[8];
#pragma unroll
    for (int g = 0; g < 4; ++g) {
      int j = (g - h) & 3;
      u[2 * g]     = f2bf_pack(acc[r][j].x, acc[r][j].y);
      u[2 * g + 1] = f2bf_pack(acc[r][j].z, acc[r][j].w);
    }
    *(uint4*)(pbase + slot)     = make_uint4(u[0], u[1], u[2], u[3]);
    *(uint4*)(pbase + slot + 4) = make_uint4(u[4], u[5], u[6], u[7]);
    lbuf[s * 65536 + node * 8 + h] = l[r];
  }
}

__global__ __launch_bounds__(256) void attn_merge_k(const unsigned* __restrict__ p0,
    const unsigned* __restrict__ p1, const unsigned* __restrict__ p2, const unsigned* __restrict__ p3,
    const float* __restrict__ lbuf, float* __restrict__ out) {
  int i = blockIdx.x * 256 + threadIdx.x;   // (node,h), 65536 total
  float L = 0.f;
#pragma unroll
  for (int s = 0; s < 8; ++s) L += lbuf[s * 65536 + i];
  float inv = 1.f / L;
  float o[16];
#pragma unroll
  for (int d = 0; d < 16; ++d) o[d] = 0.f;
  const unsigned* regs[4] = {p0, p1, p2, p3};
#pragma unroll
  for (int s = 0; s < 8; ++s) {
    const unsigned* pb = regs[s >> 1] + (size_t)(s & 1) * (NN * CC / 2) + (size_t)i * 8;
    uint4 a = *(const uint4*)pb;
    uint4 b = *(const uint4*)(pb + 4);
    unsigned u[8] = {a.x, a.y, a.z, a.w, b.x, b.y, b.z, b.w};
#pragma unroll
    for (int j = 0; j < 8; ++j) {
      o[2*j]   += bf_lo(u[j]);
      o[2*j+1] += bf_hi(u[j]);
    }
  }
  float* po = out + (size_t)i * 16;
#pragma unroll
  for (int j = 0; j < 4; ++j)
    *(float4*)(po + 4 * j) = make_float4(o[4*j] * inv, o[4*j+1] * inv, o[4*j+2] * inv, o[4*j+3] * inv);
}

// ---------------- launcher ----------------

extern "C" void kernel_launch(void* const* d_in, const int* in_sizes, int n_in,
                              void* d_out, int out_size, void* d_ws, size_t ws_size,
                              hipStream_t stream) {
  const float* x      = (const float*)d_in[0];
  const int*   ei     = (const int*)d_in[1];
  const float* bias   = (const float*)d_in[3];
  const float* conv_w = (const float*)d_in[4];
  const float* conv_b = (const float*)d_in[5];
  const float* wq = (const float*)d_in[6];
  const float* bq = (const float*)d_in[7];
  const float* wk = (const float*)d_in[8];
  const float* bk = (const float*)d_in[9];
  const float* wv = (const float*)d_in[10];
  const float* bv = (const float*)d_in[11];
  const float* wo = (const float*)d_in[12];
  const float* bo = (const float*)d_in[13];
  const float* w1 = (const float*)d_in[14];
  const float* b1 = (const float*)d_in[15];
  const float* w2 = (const float*)d_in[16];
  const float* b2 = (const float*)d_in[17];
  const float* g1 = (const float*)d_in[18];
  const float* be1 = (const float*)d_in[19];
  const float* g2 = (const float*)d_in[20];
  const float* be2 = (const float*)d_in[21];
  const float* g3 = (const float*)d_in[22];
  const float* be3 = (const float*)d_in[23];
  int E = in_sizes[1] / 2;

  float* ws = (float*)d_ws;
  const size_t NC = (size_t)NN * CC;
  float* xw     = ws;            // conv xws; then bf16 partials s=0,1
  float* h1pre  = ws + NC;
  float* qb     = ws + 2 * NC;
  float* kb     = ws + 3 * NC;
  float* vb     = ws + 4 * NC;   // V; then merged attention output
  float* h2pre  = ws + 5 * NC;   // bf16 partials s=2,3 during attn; then wo-gemm out
  float* outbuf = ws + 6 * NC;   // bf16 partials s=6,7 during attn; then combine out (MLP input)
  float* hid    = ws + 2 * NC;   // reuse qb+kb after attention
  float* h3pre  = ws + 4 * NC;   // reuse vb after wo-gemm consumed it
  float* st     = ws + 7 * NC;   // 768 floats BN sums
  float* dinv   = ws + 7 * NC + 768;
  int*   degi     = (int*)(ws + 7 * NC + 768 + NN);
  int*   rowstart = degi + NN;
  int*   cursor   = rowstart + NN + 1;
  int*   col      = cursor + NN;
  float* lbuf     = (float*)(col + E);   // 8 * 65536 floats

  hipMemsetAsync(degi, 0, NN * sizeof(int), stream);
  hipMemsetAsync(st, 0, 768 * sizeof(float), stream);

  // ---- GCN branch
  count_deg_int_k<<<(E + 255) / 256, 256, 0, stream>>>(ei + E, degi, E);
  dinv_k<<<NN / 256, 256, 0, stream>>>(degi, dinv, NN);
  scan_k<<<1, 256, 0, stream>>>(degi, rowstart, cursor);
  bucket_k<<<(E + 255) / 256, 256, 0, stream>>>(ei, ei + E, cursor, col, E);
  gemm_k<<<dim3(NN / 64, 2), 256, 0, stream>>>(x, conv_w, nullptr, nullptr, dinv, xw, NN, CC, CC, 1.f, 0);
  gather_k<<<NN / 2, 256, 0, stream>>>(rowstart, col, xw, dinv, conv_b, x, h1pre);
  bn_stats_k<<<NN / 64, 256, 0, stream>>>(h1pre, st + 0, st + 128);

  // ---- attention branch
  gemm_k<<<dim3(NN / 64, 2), 256, 0, stream>>>(x, wq, bq, nullptr, nullptr, qb, NN, CC, CC, 0.25f, 0);
  gemm_k<<<dim3(NN / 64, 2), 256, 0, stream>>>(x, wk, bk, nullptr, nullptr, kb, NN, CC, CC, 1.f, 0);
  gemm_k<<<dim3(NN / 64, 2), 256, 0, stream>>>(x, wv, bv, nullptr, nullptr, vb, NN, CC, CC, 1.f, 0);
  attn_k<<<2048, 64, 0, stream>>>(qb, kb, vb, bias,
      (unsigned*)xw, (unsigned*)h2pre, (unsigned*)d_out, (unsigned*)outbuf, lbuf);
  attn_merge_k<<<65536 / 256, 256, 0, stream>>>((unsigned*)xw, (unsigned*)h2pre,
      (unsigned*)d_out, (unsigned*)outbuf, lbuf, vb);
  gemm_k<<<dim3(NN / 64, 2), 256, 0, stream>>>(vb, wo, bo, x, nullptr, h2pre, NN, CC, CC, 1.f, 0);
  bn_stats_k<<<NN / 64, 256, 0, stream>>>(h2pre, st + 256, st + 384);

  // ---- combine + MLP (BN finalizes fused)
  combine_k<<<NC / 256, 256, 0, stream>>>(h1pre, h2pre, st, g1, be1, g2, be2, outbuf);
  gemm_k<<<dim3(NN / 64, 4), 256, 0, stream>>>(outbuf, w1, b1, nullptr, nullptr, hid, NN, 2 * CC, CC, 1.f, 1);
  gemm_k<<<dim3(NN / 64, 2), 256, 0, stream>>>(hid, w2, b2, outbuf, nullptr, h3pre, NN, CC, 2 * CC, 1.f, 0);
  bn_stats_k<<<NN / 64, 256, 0, stream>>>(h3pre, st + 512, st + 640);
  bn_apply_k<<<NC / 256, 256, 0, stream>>>(h3pre, st, g3, be3, (float*)d_out);
}

// Round 3
// 450.681 us; speedup vs baseline: 1.0531x; 1.0531x over previous
//
#include <hip/hip_runtime.h>
#include <cstddef>

#define NN 8192
#define CC 128

// ---- bf16 pack helpers ----
static __device__ inline unsigned f2bf_pack(float a, float b) {
  unsigned ua = __builtin_bit_cast(unsigned, a);
  ua += 0x7fffu + ((ua >> 16) & 1u);
  unsigned ub = __builtin_bit_cast(unsigned, b);
  ub += 0x7fffu + ((ub >> 16) & 1u);
  return (ua >> 16) | (ub & 0xffff0000u);
}
static __device__ inline float bf_lo(unsigned u) { return __builtin_bit_cast(float, u << 16); }
static __device__ inline float bf_hi(unsigned u) { return __builtin_bit_cast(float, u & 0xffff0000u); }

// ---- async global->LDS (16B per lane, no VGPR transit) ----
typedef const __attribute__((address_space(1))) void gvoid_t;
typedef __attribute__((address_space(3))) void lvoid_t;
static __device__ inline void glds16(const float* g, float* l) {
  __builtin_amdgcn_global_load_lds((gvoid_t*)g, (lvoid_t*)l, 16, 0, 0);
}

// ---------------- CSR build ----------------

__global__ __launch_bounds__(256) void count_deg_int_k(const int* __restrict__ dst, int* degi, int E) {
  int i = blockIdx.x * 256 + threadIdx.x;
  if (i < E) atomicAdd(&degi[dst[i]], 1);
}

__global__ __launch_bounds__(256) void dinv_k(const int* __restrict__ degi, float* __restrict__ dinv, int n) {
  int i = blockIdx.x * 256 + threadIdx.x;
  if (i < n) dinv[i] = rsqrtf((float)(degi[i] + 1));
}

__global__ __launch_bounds__(256) void scan_k(const int* __restrict__ degi, int* __restrict__ rowstart,
                                              int* __restrict__ cursor) {
  __shared__ int partial[256];
  int t = threadIdx.x;
  int base = t * 32;
  int local[32];
  int s = 0;
#pragma unroll
  for (int i = 0; i < 32; ++i) { local[i] = s; s += degi[base + i]; }
  partial[t] = s;
  __syncthreads();
  for (int off = 1; off < 256; off <<= 1) {
    int v = (t >= off) ? partial[t - off] : 0;
    __syncthreads();
    partial[t] += v;
    __syncthreads();
  }
  int offset = partial[t] - s;
#pragma unroll
  for (int i = 0; i < 32; ++i) {
    rowstart[base + i] = offset + local[i];
    cursor[base + i] = offset + local[i];
  }
  if (t == 255) rowstart[NN] = offset + s;
}

__global__ __launch_bounds__(256) void bucket_k(const int* __restrict__ src, const int* __restrict__ dst,
    int* __restrict__ cursor, int* __restrict__ col, int E) {
  int e = blockIdx.x * 256 + threadIdx.x;
  if (e >= E) return;
  int d = dst[e];
  int pos = atomicAdd(&cursor[d], 1);
  col[pos] = src[e];
}

// h1 = dd*(sum_in xws[s] + xws[d]) + conv_b + x   where xws = (x@W)*dinv[row]
__global__ __launch_bounds__(256) void gather_k(const int* __restrict__ rowstart, const int* __restrict__ col,
    const float* __restrict__ xws, const float* __restrict__ dinv, const float* __restrict__ cb,
    const float* __restrict__ x, float* __restrict__ h1) {
  int d = blockIdx.x * 2 + (threadIdx.x >> 7);
  int c = threadIdx.x & 127;
  int j0 = rowstart[d], j1 = rowstart[d + 1];
  float dd = dinv[d];
  float sum = 0.f;
  float v = 0.f;
  if (j0 < j1) v = xws[(size_t)col[j0] * CC + c];
  for (int j = j0; j < j1; ++j) {
    float v_next = 0.f;
    if (j + 1 < j1) v_next = xws[(size_t)col[j + 1] * CC + c];
    sum += v;
    v = v_next;
  }
  int idx = d * CC + c;
  sum += xws[idx];
  h1[idx] = sum * dd + cb[c] + x[idx];
}

// ---------------- BN helpers ----------------

__global__ __launch_bounds__(256) void bn_stats_k(const float* __restrict__ X,
    float* __restrict__ sums, float* __restrict__ sumsq) {
  int t = threadIdx.x;
  int c = t & 127, rg = t >> 7;
  int r0 = blockIdx.x * 64;
  float s = 0.f, sq = 0.f;
  for (int i = 0; i < 32; ++i) {
    float v = X[(size_t)(r0 + rg + 2 * i) * CC + c];
    s += v; sq += v * v;
  }
  atomicAdd(&sums[c], s);
  atomicAdd(&sumsq[c], sq);
}

__global__ __launch_bounds__(256) void combine_k(const float* __restrict__ h1, const float* __restrict__ h2,
    const float* __restrict__ st, const float* __restrict__ g1, const float* __restrict__ be1,
    const float* __restrict__ g2, const float* __restrict__ be2, float* __restrict__ out) {
  int idx = blockIdx.x * 256 + threadIdx.x;
  int c = idx & 127;
  float mu1 = st[c] * (1.f / NN);
  float var1 = st[128 + c] * (1.f / NN) - mu1 * mu1;
  float sc1 = g1[c] * rsqrtf(var1 + 1e-5f);
  float sh1 = be1[c] - mu1 * sc1;
  float mu2 = st[256 + c] * (1.f / NN);
  float var2 = st[384 + c] * (1.f / NN) - mu2 * mu2;
  float sc2 = g2[c] * rsqrtf(var2 + 1e-5f);
  float sh2 = be2[c] - mu2 * sc2;
  out[idx] = sc1 * h1[idx] + sh1 + sc2 * h2[idx] + sh2;
}

__global__ __launch_bounds__(256) void bn_apply_k(const float* __restrict__ h, const float* __restrict__ st,
    const float* __restrict__ g3, const float* __restrict__ be3, float* __restrict__ out) {
  int idx = blockIdx.x * 256 + threadIdx.x;
  int c = idx & 127;
  float mu = st[512 + c] * (1.f / NN);
  float var = st[640 + c] * (1.f / NN) - mu * mu;
  float sc = g3[c] * rsqrtf(var + 1e-5f);
  float sh = be3[c] - mu * sc;
  out[idx] = sc * h[idx] + sh;
}

// ---------------- fp32 GEMM ----------------
__global__ __launch_bounds__(256) void gemm_k(const float* __restrict__ A, const float* __restrict__ W,
    const float* __restrict__ bias, const float* __restrict__ resid, const float* __restrict__ dscale,
    float* __restrict__ out, int M, int N, int K, float scale, int relu) {
  __shared__ float As[64 * 132];
  __shared__ float Ws[128 * 64];
  int t = threadIdx.x;
  int ty = t >> 4, tx = t & 15;
  int row0 = blockIdx.x * 64, n0 = blockIdx.y * 64;
  float acc[4][4] = {};
  for (int kc = 0; kc < K; kc += 128) {
#pragma unroll
    for (int j = 0; j < 8; ++j) {
      int f = t + 256 * j;
      int r = f >> 5, c4 = f & 31;
      *(float4*)(As + r * 132 + c4 * 4) = *(const float4*)(A + (size_t)(row0 + r) * K + kc + c4 * 4);
    }
#pragma unroll
    for (int j = 0; j < 8; ++j) {
      int f = t + 256 * j;
      int kr = f >> 4, c4 = f & 15;
      *(float4*)(Ws + kr * 64 + c4 * 4) = *(const float4*)(W + (size_t)(kc + kr) * N + n0 + c4 * 4);
    }
    __syncthreads();
    for (int k0 = 0; k0 < 128; k0 += 4) {
      float a[4][4], b[4][4];
#pragma unroll
      for (int i = 0; i < 4; ++i) {
        float4 t4 = *(const float4*)(As + (4 * ty + i) * 132 + k0);
        a[i][0] = t4.x; a[i][1] = t4.y; a[i][2] = t4.z; a[i][3] = t4.w;
      }
#pragma unroll
      for (int kk = 0; kk < 4; ++kk) {
        float4 t4 = *(const float4*)(Ws + (k0 + kk) * 64 + 4 * tx);
        b[kk][0] = t4.x; b[kk][1] = t4.y; b[kk][2] = t4.z; b[kk][3] = t4.w;
      }
#pragma unroll
      for (int kk = 0; kk < 4; ++kk)
#pragma unroll
        for (int i = 0; i < 4; ++i)
#pragma unroll
          for (int j = 0; j < 4; ++j)
            acc[i][j] += a[i][kk] * b[kk][j];
    }
    __syncthreads();
  }
  float4 bv = make_float4(0.f, 0.f, 0.f, 0.f);
  if (bias) bv = *(const float4*)(bias + n0 + 4 * tx);
#pragma unroll
  for (int i = 0; i < 4; ++i) {
    int row = row0 + 4 * ty + i;
    float ds = dscale ? dscale[row] : 1.f;
    float4 r;
    r.x = (acc[i][0] + bv.x) * scale * ds;
    r.y = (acc[i][1] + bv.y) * scale * ds;
    r.z = (acc[i][2] + bv.z) * scale * ds;
    r.w = (acc[i][3] + bv.w) * scale * ds;
    if (relu) { r.x = fmaxf(r.x, 0.f); r.y = fmaxf(r.y, 0.f); r.z = fmaxf(r.z, 0.f); r.w = fmaxf(r.w, 0.f); }
    size_t o = (size_t)row * N + n0 + 4 * tx;
    if (resid) {
      float4 rv = *(const float4*)(resid + o);
      r.x += rv.x; r.y += rv.y; r.z += rv.z; r.w += rv.w;
    }
    *(float4*)(out + o) = r;
  }
}

// ---------------- flash attention v4: (R=2, S=8) -> 4 waves/SIMD with <=128 VGPR ----------------
// Geometry: 16 q/wave (8 qq-lanes x 2 r), 8 key-splits of 64 keys, grid 4096 single-wave blocks
// = 16 blocks/CU = 4 waves/SIMD. VGPR class <=128 (qf 32 + acc 32 + frags 32) enforced by
// __launch_bounds__(64,4). LDS 6KB/block: double-buffered 2-key chunks (K 1KB | V 1KB | bias 1KB)
// -> LDS never binds occupancy. 32 chunks per split.
// Split s = orig&7 doubles as XCD affinity: each XCD's K/V working set = 16 graphs x 64KB = 1MB,
// L2-resident; 32 co-resident q-tile blocks per (b,s) hit L2.
// K/V LDS reads broadcast across the 8 qq-lanes; h vs h+4 is the free 2-way alias; j-rotation
// kills h-stride conflicts. Bias staged 1KB/chunk with kk-rotation by q (source pre-swizzled,
// linear LDS dest as global_load_lds requires).
// Partial stores use v1's uint2 pattern (the only variant measured at 1x WRITE_SIZE).
// No max-tracking: scores O(9) << 88, raw exp safe.
__global__ __launch_bounds__(64, 4) void attn_k(const float* __restrict__ Q, const float* __restrict__ K,
    const float* __restrict__ V, const float* __restrict__ bias,
    unsigned* __restrict__ p0, unsigned* __restrict__ p1,
    unsigned* __restrict__ p2, unsigned* __restrict__ p3, float* __restrict__ lbuf) {
  __shared__ float SM[2][768];    // per buf: K[0..256) V[256..512) B[512..768)
  const int t = threadIdx.x;
  const int orig = blockIdx.x;
  const int s = orig & 7;         // split; doubles as XCD-affinity
  const int qtg = orig >> 3;      // global q-tile 0..511 (16 rows each)
  const int b = qtg >> 5;
  const int qt = qtg & 31;
  const int qq = t >> 3;
  const int h = t & 7;
  const int node_t = b * 512 + qt * 16;
  const int key0 = s * 64;
  const size_t kvb = ((size_t)b * 512 + key0) * CC;
  const float* bbase = bias + ((size_t)node_t * 512 + key0) * 8;

  // rotated Q fragments: qf[r][j] holds element group (j+h)&3 of row node_t+qq+8r, head h
  float4 qf[2][4];
#pragma unroll
  for (int r = 0; r < 2; ++r)
#pragma unroll
    for (int j = 0; j < 4; ++j)
      qf[r][j] = *(const float4*)(Q + (size_t)(node_t + qq + 8 * r) * CC + h * 16 + (((j + h) & 3) << 2));

  float4 acc[2][4];
  float l[2] = {0.f, 0.f};
#pragma unroll
  for (int r = 0; r < 2; ++r)
#pragma unroll
    for (int j = 0; j < 4; ++j) acc[r][j] = make_float4(0.f, 0.f, 0.f, 0.f);

  // stage one 2-key chunk: 3 glds16 per lane (K 1KB, V 1KB, bias 1KB)
  auto stage = [&](int ch, int bf) {
    const float* kg = K + kvb + ch * 256;    // 2 keys x 128 floats
    const float* vg = V + kvb + ch * 256;
    float* ksl = &SM[bf][0];
    float* vsl = &SM[bf][256];
    float* bsl = &SM[bf][512];
    glds16(kg + t * 4, ksl);
    glds16(vg + t * 4, vsl);
    // bias: lane t = (q, kkp, hq): q=t>>2, kkp=(t>>1)&1, hq=t&1; LDS slot q*16+kkp*8+hq*4;
    // source key kks = (kkp - q)&1 -> per q-row covers 64B contiguous [ch*64, ch*64+64)
    {
      int q = t >> 2, kkp = (t >> 1) & 1, hq = t & 1;
      int kks = (kkp - q) & 1;
      glds16(bbase + (size_t)q * 4096 + (size_t)(ch * 2 + kks) * 8 + hq * 4, bsl);
    }
  };

  stage(0, 0);
  for (int ch = 0; ch < 32; ++ch) {
    int bf = ch & 1;
    if (ch + 1 < 32) stage(ch + 1, bf ^ 1);
    asm volatile("" ::: "memory");
    if (ch + 1 < 32) __builtin_amdgcn_s_waitcnt(0x0F73);  // vmcnt(3): this chunk done, next in flight
    else             __builtin_amdgcn_s_waitcnt(0x0F70);  // vmcnt(0)
    asm volatile("" ::: "memory");
    const float* ksl = &SM[bf][0];
    const float* vsl = &SM[bf][256];
    const float* bsl = &SM[bf][512];
#pragma unroll
    for (int kk = 0; kk < 2; ++kk) {
      float4 kr[4], vr[4];
#pragma unroll
      for (int j = 0; j < 4; ++j) {
        int off = kk * 128 + h * 16 + (((j + h) & 3) << 2);
        kr[j] = *(const float4*)(ksl + off);
        vr[j] = *(const float4*)(vsl + off);
      }
#pragma unroll
      for (int r = 0; r < 2; ++r) {
        int q = qq + 8 * r;
        float sc = bsl[q * 16 + (((kk + q) & 1) << 3) + h];
#pragma unroll
        for (int j = 0; j < 4; ++j)
          sc += qf[r][j].x * kr[j].x + qf[r][j].y * kr[j].y
              + qf[r][j].z * kr[j].z + qf[r][j].w * kr[j].w;
        float p = __expf(sc);
        l[r] += p;
#pragma unroll
        for (int j = 0; j < 4; ++j) {
          acc[r][j].x += p * vr[j].x; acc[r][j].y += p * vr[j].y;
          acc[r][j].z += p * vr[j].z; acc[r][j].w += p * vr[j].w;
        }
      }
    }
  }

  // write bf16 raw-sum partials (un-rotate group order) + l — v1's uint2 store pattern
  unsigned* preg = (s < 4) ? ((s < 2) ? p0 : p1) : ((s < 6) ? p2 : p3);
  unsigned* pbase = preg + (size_t)(s & 1) * (NN * CC / 2);
#pragma unroll
  for (int r = 0; r < 2; ++r) {
    int node = node_t + qq + 8 * r;
    int slot = (node * 8 + h) * 8;
#pragma unroll
    for (int g = 0; g < 4; ++g) {
      int j = (g - h) & 3;
      unsigned u0 = f2bf_pack(acc[r][j].x, acc[r][j].y);
      unsigned u1 = f2bf_pack(acc[r][j].z, acc[r][j].w);
      *(uint2*)(pbase + slot + g * 2) = make_uint2(u0, u1);
    }
    lbuf[s * 65536 + node * 8 + h] = l[r];
  }
}

__global__ __launch_bounds__(256) void attn_merge_k(const unsigned* __restrict__ p0,
    const unsigned* __restrict__ p1, const unsigned* __restrict__ p2, const unsigned* __restrict__ p3,
    const float* __restrict__ lbuf, float* __restrict__ out) {
  int i = blockIdx.x * 256 + threadIdx.x;   // (node,h), 65536 total
  float L = 0.f;
#pragma unroll
  for (int s = 0; s < 8; ++s) L += lbuf[s * 65536 + i];
  float inv = 1.f / L;
  float o[16];
#pragma unroll
  for (int d = 0; d < 16; ++d) o[d] = 0.f;
  const unsigned* regs[4] = {p0, p1, p2, p3};
#pragma unroll
  for (int s = 0; s < 8; ++s) {
    const unsigned* pb = regs[s >> 1] + (size_t)(s & 1) * (NN * CC / 2) + (size_t)i * 8;
    uint4 a = *(const uint4*)pb;
    uint4 b = *(const uint4*)(pb + 4);
    unsigned u[8] = {a.x, a.y, a.z, a.w, b.x, b.y, b.z, b.w};
#pragma unroll
    for (int j = 0; j < 8; ++j) {
      o[2*j]   += bf_lo(u[j]);
      o[2*j+1] += bf_hi(u[j]);
    }
  }
  float* po = out + (size_t)i * 16;
#pragma unroll
  for (int j = 0; j < 4; ++j)
    *(float4*)(po + 4 * j) = make_float4(o[4*j] * inv, o[4*j+1] * inv, o[4*j+2] * inv, o[4*j+3] * inv);
}

// ---------------- launcher ----------------

extern "C" void kernel_launch(void* const* d_in, const int* in_sizes, int n_in,
                              void* d_out, int out_size, void* d_ws, size_t ws_size,
                              hipStream_t stream) {
  const float* x      = (const float*)d_in[0];
  const int*   ei     = (const int*)d_in[1];
  const float* bias   = (const float*)d_in[3];
  const float* conv_w = (const float*)d_in[4];
  const float* conv_b = (const float*)d_in[5];
  const float* wq = (const float*)d_in[6];
  const float* bq = (const float*)d_in[7];
  const float* wk = (const float*)d_in[8];
  const float* bk = (const float*)d_in[9];
  const float* wv = (const float*)d_in[10];
  const float* bv = (const float*)d_in[11];
  const float* wo = (const float*)d_in[12];
  const float* bo = (const float*)d_in[13];
  const float* w1 = (const float*)d_in[14];
  const float* b1 = (const float*)d_in[15];
  const float* w2 = (const float*)d_in[16];
  const float* b2 = (const float*)d_in[17];
  const float* g1 = (const float*)d_in[18];
  const float* be1 = (const float*)d_in[19];
  const float* g2 = (const float*)d_in[20];
  const float* be2 = (const float*)d_in[21];
  const float* g3 = (const float*)d_in[22];
  const float* be3 = (const float*)d_in[23];
  int E = in_sizes[1] / 2;

  float* ws = (float*)d_ws;
  const size_t NC = (size_t)NN * CC;
  float* xw     = ws;            // conv xws; then bf16 partials s=0,1
  float* h1pre  = ws + NC;
  float* qb     = ws + 2 * NC;
  float* kb     = ws + 3 * NC;
  float* vb     = ws + 4 * NC;   // V; then merged attention output
  float* h2pre  = ws + 5 * NC;   // bf16 partials s=2,3 during attn; then wo-gemm out
  float* outbuf = ws + 6 * NC;   // bf16 partials s=6,7 during attn; then combine out (MLP input)
  float* hid    = ws + 2 * NC;   // reuse qb+kb after attention
  float* h3pre  = ws + 4 * NC;   // reuse vb after wo-gemm consumed it
  float* st     = ws + 7 * NC;   // 768 floats BN sums
  float* dinv   = ws + 7 * NC + 768;
  int*   degi     = (int*)(ws + 7 * NC + 768 + NN);
  int*   rowstart = degi + NN;
  int*   cursor   = rowstart + NN + 1;
  int*   col      = cursor + NN;
  float* lbuf     = (float*)(col + E);   // 8 * 65536 floats

  hipMemsetAsync(degi, 0, NN * sizeof(int), stream);
  hipMemsetAsync(st, 0, 768 * sizeof(float), stream);

  // ---- GCN branch
  count_deg_int_k<<<(E + 255) / 256, 256, 0, stream>>>(ei + E, degi, E);
  dinv_k<<<NN / 256, 256, 0, stream>>>(degi, dinv, NN);
  scan_k<<<1, 256, 0, stream>>>(degi, rowstart, cursor);
  bucket_k<<<(E + 255) / 256, 256, 0, stream>>>(ei, ei + E, cursor, col, E);
  gemm_k<<<dim3(NN / 64, 2), 256, 0, stream>>>(x, conv_w, nullptr, nullptr, dinv, xw, NN, CC, CC, 1.f, 0);
  gather_k<<<NN / 2, 256, 0, stream>>>(rowstart, col, xw, dinv, conv_b, x, h1pre);
  bn_stats_k<<<NN / 64, 256, 0, stream>>>(h1pre, st + 0, st + 128);

  // ---- attention branch
  gemm_k<<<dim3(NN / 64, 2), 256, 0, stream>>>(x, wq, bq, nullptr, nullptr, qb, NN, CC, CC, 0.25f, 0);
  gemm_k<<<dim3(NN / 64, 2), 256, 0, stream>>>(x, wk, bk, nullptr, nullptr, kb, NN, CC, CC, 1.f, 0);
  gemm_k<<<dim3(NN / 64, 2), 256, 0, stream>>>(x, wv, bv, nullptr, nullptr, vb, NN, CC, CC, 1.f, 0);
  attn_k<<<4096, 64, 0, stream>>>(qb, kb, vb, bias,
      (unsigned*)xw, (unsigned*)h2pre, (unsigned*)d_out, (unsigned*)outbuf, lbuf);
  attn_merge_k<<<65536 / 256, 256, 0, stream>>>((unsigned*)xw, (unsigned*)h2pre,
      (unsigned*)d_out, (unsigned*)outbuf, lbuf, vb);
  gemm_k<<<dim3(NN / 64, 2), 256, 0, stream>>>(vb, wo, bo, x, nullptr, h2pre, NN, CC, CC, 1.f, 0);
  bn_stats_k<<<NN / 64, 256, 0, stream>>>(h2pre, st + 256, st + 384);

  // ---- combine + MLP (BN finalizes fused)
  combine_k<<<NC / 256, 256, 0, stream>>>(h1pre, h2pre, st, g1, be1, g2, be2, outbuf);
  gemm_k<<<dim3(NN / 64, 4), 256, 0, stream>>>(outbuf, w1, b1, nullptr, nullptr, hid, NN, 2 * CC, CC, 1.f, 1);
  gemm_k<<<dim3(NN / 64, 2), 256, 0, stream>>>(hid, w2, b2, outbuf, nullptr, h3pre, NN, CC, 2 * CC, 1.f, 0);
  bn_stats_k<<<NN / 64, 256, 0, stream>>>(h3pre, st + 512, st + 640);
  bn_apply_k<<<NC / 256, 256, 0, stream>>>(h3pre, st, g3, be3, (float*)d_out);
}

// Round 4
// 422.700 us; speedup vs baseline: 1.1228x; 1.0662x over previous
//
#include <hip/hip_runtime.h>
#include <cstddef>

#define NN 8192
#define CC 128

typedef unsigned short u16;
typedef _Float16 half_t;
typedef _Float16 v4h __attribute__((ext_vector_type(4)));
typedef float v4f __attribute__((ext_vector_type(4)));

// ---- bf16 helpers ----
static __device__ inline u16 f2bf1(float x) {
  unsigned u = __builtin_bit_cast(unsigned, x);
  u += 0x7fffu + ((u >> 16) & 1u);
  return (u16)(u >> 16);
}
static __device__ inline float bf_lo(unsigned u) { return __builtin_bit_cast(float, u << 16); }
static __device__ inline float bf_hi(unsigned u) { return __builtin_bit_cast(float, u & 0xffff0000u); }

// ---- LDS address (AS3 offset) ----
typedef __attribute__((address_space(3))) void lvoid_t;
static __device__ inline unsigned lds_addr(void* p) {
  return (unsigned)(unsigned long long)(lvoid_t*)p;
}

// ---------------- CSR build ----------------

__global__ __launch_bounds__(256) void count_deg_int_k(const int* __restrict__ dst, int* degi, int E) {
  int i = blockIdx.x * 256 + threadIdx.x;
  if (i < E) atomicAdd(&degi[dst[i]], 1);
}

__global__ __launch_bounds__(256) void dinv_k(const int* __restrict__ degi, float* __restrict__ dinv, int n) {
  int i = blockIdx.x * 256 + threadIdx.x;
  if (i < n) dinv[i] = rsqrtf((float)(degi[i] + 1));
}

__global__ __launch_bounds__(256) void scan_k(const int* __restrict__ degi, int* __restrict__ rowstart,
                                              int* __restrict__ cursor) {
  __shared__ int partial[256];
  int t = threadIdx.x;
  int base = t * 32;
  int local[32];
  int s = 0;
#pragma unroll
  for (int i = 0; i < 32; ++i) { local[i] = s; s += degi[base + i]; }
  partial[t] = s;
  __syncthreads();
  for (int off = 1; off < 256; off <<= 1) {
    int v = (t >= off) ? partial[t - off] : 0;
    __syncthreads();
    partial[t] += v;
    __syncthreads();
  }
  int offset = partial[t] - s;
#pragma unroll
  for (int i = 0; i < 32; ++i) {
    rowstart[base + i] = offset + local[i];
    cursor[base + i] = offset + local[i];
  }
  if (t == 255) rowstart[NN] = offset + s;
}

__global__ __launch_bounds__(256) void bucket_k(const int* __restrict__ src, const int* __restrict__ dst,
    int* __restrict__ cursor, int* __restrict__ col, int E) {
  int e = blockIdx.x * 256 + threadIdx.x;
  if (e >= E) return;
  int d = dst[e];
  int pos = atomicAdd(&cursor[d], 1);
  col[pos] = src[e];
}

// h1 = dd*(sum_in xws[s] + xws[d]) + conv_b + x   where xws = (x@W)*dinv[row]
__global__ __launch_bounds__(256) void gather_k(const int* __restrict__ rowstart, const int* __restrict__ col,
    const float* __restrict__ xws, const float* __restrict__ dinv, const float* __restrict__ cb,
    const float* __restrict__ x, float* __restrict__ h1) {
  int d = blockIdx.x * 2 + (threadIdx.x >> 7);
  int c = threadIdx.x & 127;
  int j0 = rowstart[d], j1 = rowstart[d + 1];
  float dd = dinv[d];
  float sum = 0.f;
  float v = 0.f;
  if (j0 < j1) v = xws[(size_t)col[j0] * CC + c];
  for (int j = j0; j < j1; ++j) {
    float v_next = 0.f;
    if (j + 1 < j1) v_next = xws[(size_t)col[j + 1] * CC + c];
    sum += v;
    v = v_next;
  }
  int idx = d * CC + c;
  sum += xws[idx];
  h1[idx] = sum * dd + cb[c] + x[idx];
}

// ---------------- BN helpers ----------------

__global__ __launch_bounds__(256) void bn_stats_k(const float* __restrict__ X,
    float* __restrict__ sums, float* __restrict__ sumsq) {
  int t = threadIdx.x;
  int c = t & 127, rg = t >> 7;
  int r0 = blockIdx.x * 64;
  float s = 0.f, sq = 0.f;
  for (int i = 0; i < 32; ++i) {
    float v = X[(size_t)(r0 + rg + 2 * i) * CC + c];
    s += v; sq += v * v;
  }
  atomicAdd(&sums[c], s);
  atomicAdd(&sumsq[c], sq);
}

__global__ __launch_bounds__(256) void combine_k(const float* __restrict__ h1, const float* __restrict__ h2,
    const float* __restrict__ st, const float* __restrict__ g1, const float* __restrict__ be1,
    const float* __restrict__ g2, const float* __restrict__ be2, float* __restrict__ out) {
  int idx = blockIdx.x * 256 + threadIdx.x;
  int c = idx & 127;
  float mu1 = st[c] * (1.f / NN);
  float var1 = st[128 + c] * (1.f / NN) - mu1 * mu1;
  float sc1 = g1[c] * rsqrtf(var1 + 1e-5f);
  float sh1 = be1[c] - mu1 * sc1;
  float mu2 = st[256 + c] * (1.f / NN);
  float var2 = st[384 + c] * (1.f / NN) - mu2 * mu2;
  float sc2 = g2[c] * rsqrtf(var2 + 1e-5f);
  float sh2 = be2[c] - mu2 * sc2;
  out[idx] = sc1 * h1[idx] + sh1 + sc2 * h2[idx] + sh2;
}

__global__ __launch_bounds__(256) void bn_apply_k(const float* __restrict__ h, const float* __restrict__ st,
    const float* __restrict__ g3, const float* __restrict__ be3, float* __restrict__ out) {
  int idx = blockIdx.x * 256 + threadIdx.x;
  int c = idx & 127;
  float mu = st[512 + c] * (1.f / NN);
  float var = st[640 + c] * (1.f / NN) - mu * mu;
  float sc = g3[c] * rsqrtf(var + 1e-5f);
  float sh = be3[c] - mu * sc;
  out[idx] = sc * h[idx] + sh;
}

// ---------------- fp32 GEMM (optional fp16-packed output for Q/K/V) ----------------
__global__ __launch_bounds__(256) void gemm_k(const float* __restrict__ A, const float* __restrict__ W,
    const float* __restrict__ bias, const float* __restrict__ resid, const float* __restrict__ dscale,
    float* __restrict__ out, int M, int N, int K, float scale, int relu, int ofp16) {
  __shared__ float As[64 * 132];
  __shared__ float Ws[128 * 64];
  int t = threadIdx.x;
  int ty = t >> 4, tx = t & 15;
  int row0 = blockIdx.x * 64, n0 = blockIdx.y * 64;
  float acc[4][4] = {};
  for (int kc = 0; kc < K; kc += 128) {
#pragma unroll
    for (int j = 0; j < 8; ++j) {
      int f = t + 256 * j;
      int r = f >> 5, c4 = f & 31;
      *(float4*)(As + r * 132 + c4 * 4) = *(const float4*)(A + (size_t)(row0 + r) * K + kc + c4 * 4);
    }
#pragma unroll
    for (int j = 0; j < 8; ++j) {
      int f = t + 256 * j;
      int kr = f >> 4, c4 = f & 15;
      *(float4*)(Ws + kr * 64 + c4 * 4) = *(const float4*)(W + (size_t)(kc + kr) * N + n0 + c4 * 4);
    }
    __syncthreads();
    for (int k0 = 0; k0 < 128; k0 += 4) {
      float a[4][4], b[4][4];
#pragma unroll
      for (int i = 0; i < 4; ++i) {
        float4 t4 = *(const float4*)(As + (4 * ty + i) * 132 + k0);
        a[i][0] = t4.x; a[i][1] = t4.y; a[i][2] = t4.z; a[i][3] = t4.w;
      }
#pragma unroll
      for (int kk = 0; kk < 4; ++kk) {
        float4 t4 = *(const float4*)(Ws + (k0 + kk) * 64 + 4 * tx);
        b[kk][0] = t4.x; b[kk][1] = t4.y; b[kk][2] = t4.z; b[kk][3] = t4.w;
      }
#pragma unroll
      for (int kk = 0; kk < 4; ++kk)
#pragma unroll
        for (int i = 0; i < 4; ++i)
#pragma unroll
          for (int j = 0; j < 4; ++j)
            acc[i][j] += a[i][kk] * b[kk][j];
    }
    __syncthreads();
  }
  float4 bv = make_float4(0.f, 0.f, 0.f, 0.f);
  if (bias) bv = *(const float4*)(bias + n0 + 4 * tx);
#pragma unroll
  for (int i = 0; i < 4; ++i) {
    int row = row0 + 4 * ty + i;
    float ds = dscale ? dscale[row] : 1.f;
    float4 r;
    r.x = (acc[i][0] + bv.x) * scale * ds;
    r.y = (acc[i][1] + bv.y) * scale * ds;
    r.z = (acc[i][2] + bv.z) * scale * ds;
    r.w = (acc[i][3] + bv.w) * scale * ds;
    if (relu) { r.x = fmaxf(r.x, 0.f); r.y = fmaxf(r.y, 0.f); r.z = fmaxf(r.z, 0.f); r.w = fmaxf(r.w, 0.f); }
    size_t o = (size_t)row * N + n0 + 4 * tx;
    if (ofp16) {
      half_t* oh = (half_t*)out;
      v4h hv;
      hv[0] = (half_t)r.x; hv[1] = (half_t)r.y; hv[2] = (half_t)r.z; hv[3] = (half_t)r.w;
      *(v4h*)(oh + o) = hv;
    } else {
      if (resid) {
        float4 rv = *(const float4*)(resid + o);
        r.x += rv.x; r.y += rv.y; r.z += rv.z; r.w += rv.w;
      }
      *(float4*)(out + o) = r;
    }
  }
}

// ---------------- flash attention v5: MFMA (16x16x16 f16) ----------------
// Wave = 16 q-rows x 64 keys x 8 heads; S=8 splits; grid 4096 single-wave blocks.
// Per 16-key chunk:
//   ST^T[key][q] = mfma(A=K_frag, B=Q_frag) per head (8 MFMAs). Lane holds (q=l&15,
//   keys=(l>>4)*4+reg) -- exactly the A-layout P needs for PV, so softmax is lane-local.
//   bias: direct global float4 (L3-resident 134MB stream; paired hh instrs complete sectors).
//   p = exp(score-4) (shift keeps P in fp16 range; ratio-invariant across merge).
//   PV: oacc = mfma(A=P_fp16, B=V_frag, oacc) per head. V staged in LDS as [hd][kg][4][16]
//   fp16 subtiles, read via ds_read_b64_tr_b16 (HW transpose; 8 reads/chunk).
// K/Q read direct from global fp16 (L2-resident slices; no broadcast waste).
// Partials: per-wave-contiguous 4KB [tile][hd][reg][lane] bf16 (kills v3/v4's 5x write amp).
__global__ __launch_bounds__(64, 3) void attn_k(const half_t* __restrict__ Qh,
    const half_t* __restrict__ Kh, const half_t* __restrict__ Vh, const float* __restrict__ bias,
    u16* __restrict__ p0, u16* __restrict__ p1, u16* __restrict__ p2, u16* __restrict__ p3,
    float* __restrict__ lbuf) {
  __shared__ u16 VL[2][2048];    // 2 x 4KB: V chunk as [hd(8)][kg(4)][km(4)][dm(16)] fp16
  const int t = threadIdx.x;
  const int orig = blockIdx.x;
  const int s = orig & 7;        // split (XCD affinity)
  const int qtg = orig >> 3;     // q-tile 0..511 (16 rows)
  const int b = qtg >> 5;
  const int key0 = s * 64;
  const int node_t = qtg * 16;   // == b*512 + (qtg&31)*16
  const int kb0 = b * 512 + key0;
  const int lq = t & 15;
  const int lg = t >> 4;

  // Q fragments (B-layout): lane holds Q[node_t+lq][hd*16 + lg*4 .. +3]
  v4h qf[8];
#pragma unroll
  for (int hd = 0; hd < 8; ++hd)
    qf[hd] = *(const v4h*)(Qh + (size_t)(node_t + lq) * CC + hd * 16 + lg * 4);

  v4f oacc[8];
  float lacc[8];
#pragma unroll
  for (int hd = 0; hd < 8; ++hd) { oacc[hd] = (v4f){0.f, 0.f, 0.f, 0.f}; lacc[hd] = 0.f; }

  // V staging decode (lane-fixed): instr i, lane t -> LDS ushort o = i*512 + t*8
  // hd = i*2 + (t>>5), kg = (t>>3)&3, km = (t>>1)&3, dm0 = (t&1)*8
  const int v_hdb = t >> 5;
  const int v_kg = (t >> 3) & 3;
  const int v_km = (t >> 1) & 3;
  const int v_dm0 = (t & 1) * 8;
  uint4 vreg[4];

  auto vload = [&](int ch) {
#pragma unroll
    for (int i = 0; i < 4; ++i)
      vreg[i] = *(const uint4*)(Vh + (size_t)(kb0 + ch * 16 + v_kg * 4 + v_km) * CC
                                + (i * 2 + v_hdb) * 16 + v_dm0);
  };
  auto vwrite = [&](int bf) {
#pragma unroll
    for (int i = 0; i < 4; ++i)
      *(uint4*)&VL[bf][i * 512 + t * 8] = vreg[i];
  };

  const unsigned lbase = lds_addr(&VL[0][0]);
  const float* bb = bias + ((size_t)node_t * 512 + key0) * 8 + (size_t)lq * 4096;

  // prologue: stage chunk 0
  vload(0);
  vwrite(0);

  for (int ch = 0; ch < 4; ++ch) {
    const int bf = ch & 1;
    if (ch < 3) vload(ch + 1);

    // K fragments (A-layout): lane holds K[kb0+ch*16+lq][hd*16 + lg*4 .. +3]
    v4h kf[8];
#pragma unroll
    for (int hd = 0; hd < 8; ++hd)
      kf[hd] = *(const v4h*)(Kh + (size_t)(kb0 + ch * 16 + lq) * CC + hd * 16 + lg * 4);

    // drain prior ds_writes, then HW-transpose-read V fragments for this chunk
    asm volatile("s_waitcnt lgkmcnt(0)" ::: "memory");
    __builtin_amdgcn_sched_barrier(0);
    unsigned va = lbase + (unsigned)(bf * 4096) + (unsigned)(t * 8);
    unsigned long long vfr[8];
#pragma unroll
    for (int hd = 0; hd < 8; ++hd)
      asm volatile("ds_read_b64_tr_b16 %0, %1 offset:%2"
                   : "=v"(vfr[hd]) : "v"(va), "i"(hd * 512));
    asm volatile("s_waitcnt lgkmcnt(0)" ::: "memory");
    __builtin_amdgcn_sched_barrier(0);

    if (ch < 3) vwrite(bf ^ 1);   // stage next chunk into other buffer

    const v4f z = (v4f){0.f, 0.f, 0.f, 0.f};
#pragma unroll
    for (int hg = 0; hg < 2; ++hg) {
      // bias float4 per (reg): bias[node_t+lq][key0+ch*16+lg*4+reg][hg*4 .. +3]
      v4f bfr[4];
#pragma unroll
      for (int reg = 0; reg < 4; ++reg)
        bfr[reg] = *(const v4f*)(bb + (size_t)(ch * 16 + lg * 4 + reg) * 8 + hg * 4);

      v4f stv[4];
#pragma unroll
      for (int j = 0; j < 4; ++j)
        stv[j] = __builtin_amdgcn_mfma_f32_16x16x16f16(kf[hg * 4 + j], qf[hg * 4 + j], z, 0, 0, 0);

#pragma unroll
      for (int j = 0; j < 4; ++j) {
        const int hd = hg * 4 + j;
        float pr0 = __expf(stv[j][0] + bfr[0][j] - 4.f);
        float pr1 = __expf(stv[j][1] + bfr[1][j] - 4.f);
        float pr2 = __expf(stv[j][2] + bfr[2][j] - 4.f);
        float pr3 = __expf(stv[j][3] + bfr[3][j] - 4.f);
        lacc[hd] += pr0 + pr1 + pr2 + pr3;
        unsigned u0 = __builtin_bit_cast(unsigned, __builtin_amdgcn_cvt_pkrtz(pr0, pr1));
        unsigned u1 = __builtin_bit_cast(unsigned, __builtin_amdgcn_cvt_pkrtz(pr2, pr3));
        uint2 pu = make_uint2(u0, u1);
        v4h pa = __builtin_bit_cast(v4h, pu);
        v4h vf = __builtin_bit_cast(v4h, vfr[hd]);
        oacc[hd] = __builtin_amdgcn_mfma_f32_16x16x16f16(pa, vf, oacc[hd], 0, 0, 0);
      }
    }
  }

  // ---- epilogue ----
  // partials: lane holds O[q = lg*4+reg][d = hd*16+lq]; layout [tile][hd][reg][lane]
  u16* preg = (s < 4) ? ((s < 2) ? p0 : p1) : ((s < 6) ? p2 : p3);
  u16* pbase = preg + (size_t)(s & 1) * ((size_t)NN * CC);
#pragma unroll
  for (int hd = 0; hd < 8; ++hd)
#pragma unroll
    for (int reg = 0; reg < 4; ++reg)
      pbase[(((size_t)qtg * 8 + hd) * 4 + reg) * 64 + t] = f2bf1(oacc[hd][reg]);

  // l sums: lane-local (q=lq) partial over its key-groups -> reduce over lg (xor 16,32)
#pragma unroll
  for (int hd = 0; hd < 8; ++hd) {
    float v = lacc[hd];
    v += __shfl_xor(v, 16);
    v += __shfl_xor(v, 32);
    lacc[hd] = v;
  }
  if (t < 16) {
#pragma unroll
    for (int hd = 0; hd < 8; ++hd)
      lbuf[s * 65536 + (node_t + t) * 8 + hd] = lacc[hd];
  }
}

__global__ __launch_bounds__(256) void attn_merge_k(const u16* __restrict__ p0,
    const u16* __restrict__ p1, const u16* __restrict__ p2, const u16* __restrict__ p3,
    const float* __restrict__ lbuf, float* __restrict__ out) {
  int i = blockIdx.x * 256 + threadIdx.x;   // (node,h), 65536 total
  int node = i >> 3, h = i & 7;
  int tile = node >> 4, q = node & 15;
  float L = 0.f;
#pragma unroll
  for (int s = 0; s < 8; ++s) L += lbuf[s * 65536 + i];
  float inv = 1.f / L;
  float o[16];
#pragma unroll
  for (int d = 0; d < 16; ++d) o[d] = 0.f;
  const u16* regs[4] = {p0, p1, p2, p3};
  size_t base = (((size_t)tile * 8 + h) * 4 + (q & 3)) * 64 + (q >> 2) * 16;
#pragma unroll
  for (int s = 0; s < 8; ++s) {
    const u16* pb = regs[s >> 1] + (size_t)(s & 1) * ((size_t)NN * CC) + base;
    uint4 a = *(const uint4*)pb;
    uint4 b = *(const uint4*)(pb + 8);
    unsigned u[8] = {a.x, a.y, a.z, a.w, b.x, b.y, b.z, b.w};
#pragma unroll
    for (int j = 0; j < 8; ++j) {
      o[2 * j]     += bf_lo(u[j]);
      o[2 * j + 1] += bf_hi(u[j]);
    }
  }
  float* po = out + (size_t)i * 16;
#pragma unroll
  for (int j = 0; j < 4; ++j)
    *(float4*)(po + 4 * j) = make_float4(o[4*j] * inv, o[4*j+1] * inv, o[4*j+2] * inv, o[4*j+3] * inv);
}

// ---------------- launcher ----------------

extern "C" void kernel_launch(void* const* d_in, const int* in_sizes, int n_in,
                              void* d_out, int out_size, void* d_ws, size_t ws_size,
                              hipStream_t stream) {
  const float* x      = (const float*)d_in[0];
  const int*   ei     = (const int*)d_in[1];
  const float* bias   = (const float*)d_in[3];
  const float* conv_w = (const float*)d_in[4];
  const float* conv_b = (const float*)d_in[5];
  const float* wq = (const float*)d_in[6];
  const float* bq = (const float*)d_in[7];
  const float* wk = (const float*)d_in[8];
  const float* bk = (const float*)d_in[9];
  const float* wv = (const float*)d_in[10];
  const float* bv = (const float*)d_in[11];
  const float* wo = (const float*)d_in[12];
  const float* bo = (const float*)d_in[13];
  const float* w1 = (const float*)d_in[14];
  const float* b1 = (const float*)d_in[15];
  const float* w2 = (const float*)d_in[16];
  const float* b2 = (const float*)d_in[17];
  const float* g1 = (const float*)d_in[18];
  const float* be1 = (const float*)d_in[19];
  const float* g2 = (const float*)d_in[20];
  const float* be2 = (const float*)d_in[21];
  const float* g3 = (const float*)d_in[22];
  const float* be3 = (const float*)d_in[23];
  int E = in_sizes[1] / 2;

  float* ws = (float*)d_ws;
  const size_t NC = (size_t)NN * CC;
  float* xw     = ws;            // conv xws; then bf16 partials s=0,1
  float* h1pre  = ws + NC;
  float* qb     = ws + 2 * NC;   // fp16 Q (2MB used)
  float* kb     = ws + 3 * NC;   // fp16 K
  float* vb     = ws + 4 * NC;   // fp16 V; then merged attention output (f32, 4MB)
  float* h2pre  = ws + 5 * NC;   // bf16 partials s=2,3 during attn; then wo-gemm out
  float* outbuf = ws + 6 * NC;   // bf16 partials s=6,7 during attn; then combine out (MLP input)
  float* hid    = ws + 2 * NC;   // reuse qb+kb after attention
  float* h3pre  = ws + 4 * NC;   // reuse vb after wo-gemm consumed it
  float* st     = ws + 7 * NC;   // 768 floats BN sums
  float* dinv   = ws + 7 * NC + 768;
  int*   degi     = (int*)(ws + 7 * NC + 768 + NN);
  int*   rowstart = degi + NN;
  int*   cursor   = rowstart + NN + 1;
  int*   col      = cursor + NN;
  float* lbuf     = (float*)(col + E);   // 8 * 65536 floats

  hipMemsetAsync(degi, 0, NN * sizeof(int), stream);
  hipMemsetAsync(st, 0, 768 * sizeof(float), stream);

  // ---- GCN branch
  count_deg_int_k<<<(E + 255) / 256, 256, 0, stream>>>(ei + E, degi, E);
  dinv_k<<<NN / 256, 256, 0, stream>>>(degi, dinv, NN);
  scan_k<<<1, 256, 0, stream>>>(degi, rowstart, cursor);
  bucket_k<<<(E + 255) / 256, 256, 0, stream>>>(ei, ei + E, cursor, col, E);
  gemm_k<<<dim3(NN / 64, 2), 256, 0, stream>>>(x, conv_w, nullptr, nullptr, dinv, xw, NN, CC, CC, 1.f, 0, 0);
  gather_k<<<NN / 2, 256, 0, stream>>>(rowstart, col, xw, dinv, conv_b, x, h1pre);
  bn_stats_k<<<NN / 64, 256, 0, stream>>>(h1pre, st + 0, st + 128);

  // ---- attention branch (Q/K/V as fp16)
  gemm_k<<<dim3(NN / 64, 2), 256, 0, stream>>>(x, wq, bq, nullptr, nullptr, qb, NN, CC, CC, 0.25f, 0, 1);
  gemm_k<<<dim3(NN / 64, 2), 256, 0, stream>>>(x, wk, bk, nullptr, nullptr, kb, NN, CC, CC, 1.f, 0, 1);
  gemm_k<<<dim3(NN / 64, 2), 256, 0, stream>>>(x, wv, bv, nullptr, nullptr, vb, NN, CC, CC, 1.f, 0, 1);
  attn_k<<<4096, 64, 0, stream>>>((const half_t*)qb, (const half_t*)kb, (const half_t*)vb, bias,
      (u16*)xw, (u16*)h2pre, (u16*)d_out, (u16*)outbuf, lbuf);
  attn_merge_k<<<65536 / 256, 256, 0, stream>>>((const u16*)xw, (const u16*)h2pre,
      (const u16*)d_out, (const u16*)outbuf, lbuf, vb);
  gemm_k<<<dim3(NN / 64, 2), 256, 0, stream>>>(vb, wo, bo, x, nullptr, h2pre, NN, CC, CC, 1.f, 0, 0);
  bn_stats_k<<<NN / 64, 256, 0, stream>>>(h2pre, st + 256, st + 384);

  // ---- combine + MLP (BN finalizes fused)
  combine_k<<<NC / 256, 256, 0, stream>>>(h1pre, h2pre, st, g1, be1, g2, be2, outbuf);
  gemm_k<<<dim3(NN / 64, 4), 256, 0, stream>>>(outbuf, w1, b1, nullptr, nullptr, hid, NN, 2 * CC, CC, 1.f, 1, 0);
  gemm_k<<<dim3(NN / 64, 2), 256, 0, stream>>>(hid, w2, b2, outbuf, nullptr, h3pre, NN, CC, 2 * CC, 1.f, 0, 0);
  bn_stats_k<<<NN / 64, 256, 0, stream>>>(h3pre, st + 512, st + 640);
  bn_apply_k<<<NC / 256, 256, 0, stream>>>(h3pre, st, g3, be3, (float*)d_out);
}